// Round 10
// baseline (398.557 us; speedup 1.0000x reference)
//
#include <hip/hip_runtime.h>
#include <math.h>

#define BDIM 2
#define TT 1024
#define NH 8
#define HD 64
#define NTOPK 16
#define NBH 16     // BDIM*NH
#define NTOK 16384 // NBH*TT

// ---------------------------------------------------------------------------
// Collapse the linear-linear pair MLPs into 128-dim fp64 vectors.
// ---------------------------------------------------------------------------
__global__ __launch_bounds__(256) void k_collapse64(
    const float* __restrict__ Wpi, const float* __restrict__ bpi,
    const float* __restrict__ Wpo, const float* __restrict__ bpo,
    const float* __restrict__ Wti, const float* __restrict__ bti,
    const float* __restrict__ Wto, const float* __restrict__ bto,
    double* __restrict__ wphid, double* __restrict__ wtaud,
    double* __restrict__ ccd) {
  int tid = threadIdx.x;
  int blk = blockIdx.x;
  if (blk < 16) {
    int r = blk * 16 + (tid >> 4);
    int l = tid & 15;
    double s = 0.;
    if (r < 128) {
      for (int i = 0; i < 32; ++i)
        s += (double)Wpi[r * 512 + l + 16 * i] * (double)Wpo[l + 16 * i];
    } else {
      int rr = r - 128;
      for (int i = 0; i < 16; ++i)
        s += (double)Wti[rr * 256 + l + 16 * i] * (double)Wto[l + 16 * i];
    }
#pragma unroll
    for (int off = 8; off >= 1; off >>= 1) s += __shfl_xor(s, off, 64);
    if (l == 0) {
      if (r < 128) wphid[r] = s;
      else wtaud[r - 128] = s;
    }
  } else {
    int lane = tid & 63;
    if (tid < 64) {
      double p = 0.;
      for (int c = lane; c < 512; c += 64) p += (double)bpi[c] * (double)Wpo[c];
#pragma unroll
      for (int off = 32; off >= 1; off >>= 1) p += __shfl_xor(p, off, 64);
      if (lane == 0) ccd[0] = p + (double)bpo[0];
    } else if (tid < 128) {
      double p = 0.;
      for (int c = lane; c < 256; c += 64) p += (double)bti[c] * (double)Wto[c];
#pragma unroll
      for (int off = 32; off >= 1; off >>= 1) p += __shfl_xor(p, off, 64);
      if (lane == 0) ccd[1] = p + (double)bto[0];
    }
  }
}

// ---------------------------------------------------------------------------
// fp32 GEMM 64x64 tile, BK=32, strict sequential-k fmaf per output element
// (BLAS-order rounding — required for reference-matching top-k selection).
// 768 blocks for qkv (3 rounds of 256 CUs) — r9's 128-tile starved the grid.
// ---------------------------------------------------------------------------
__device__ __forceinline__ void gemm_body(
    const float* __restrict__ A, const float* __restrict__ W,
    const float* __restrict__ bias, float* __restrict__ out,
    int bm, int bn, int mode) {
  __shared__ float As[32][68];
  __shared__ float Bs[32][64];
  const int tid = threadIdx.x;
  const int tx = tid & 15;
  const int ty = tid >> 4;
  float acc[4][4] = {{0.f, 0.f, 0.f, 0.f}};
  for (int k0 = 0; k0 < 512; k0 += 32) {
#pragma unroll
    for (int i = 0; i < 2; ++i) {
      int idx = i * 256 + tid;
      int row = idx >> 3;
      int c4 = (idx & 7) << 2;
      float4 av = *(const float4*)&A[(bm + row) * 512 + k0 + c4];
      As[c4 + 0][row] = av.x;
      As[c4 + 1][row] = av.y;
      As[c4 + 2][row] = av.z;
      As[c4 + 3][row] = av.w;
    }
#pragma unroll
    for (int i = 0; i < 2; ++i) {
      int idx = i * 256 + tid;
      int br = idx >> 4;
      int bc = (idx & 15) << 2;
      *(float4*)&Bs[br][bc] = *(const float4*)&W[(k0 + br) * 512 + bn + bc];
    }
    __syncthreads();
#pragma unroll
    for (int kk = 0; kk < 32; ++kk) {
      float4 a = *(const float4*)&As[kk][ty * 4];
      float4 b = *(const float4*)&Bs[kk][tx << 2];
      acc[0][0] = fmaf(a.x, b.x, acc[0][0]);
      acc[0][1] = fmaf(a.x, b.y, acc[0][1]);
      acc[0][2] = fmaf(a.x, b.z, acc[0][2]);
      acc[0][3] = fmaf(a.x, b.w, acc[0][3]);
      acc[1][0] = fmaf(a.y, b.x, acc[1][0]);
      acc[1][1] = fmaf(a.y, b.y, acc[1][1]);
      acc[1][2] = fmaf(a.y, b.z, acc[1][2]);
      acc[1][3] = fmaf(a.y, b.w, acc[1][3]);
      acc[2][0] = fmaf(a.z, b.x, acc[2][0]);
      acc[2][1] = fmaf(a.z, b.y, acc[2][1]);
      acc[2][2] = fmaf(a.z, b.z, acc[2][2]);
      acc[2][3] = fmaf(a.z, b.w, acc[2][3]);
      acc[3][0] = fmaf(a.w, b.x, acc[3][0]);
      acc[3][1] = fmaf(a.w, b.y, acc[3][1]);
      acc[3][2] = fmaf(a.w, b.z, acc[3][2]);
      acc[3][3] = fmaf(a.w, b.w, acc[3][3]);
    }
    __syncthreads();
  }
#pragma unroll
  for (int i = 0; i < 4; ++i) {
    int row = bm + ty * 4 + i;
    float4 r;
    r.x = acc[i][0] + bias[bn + tx * 4 + 0];
    r.y = acc[i][1] + bias[bn + tx * 4 + 1];
    r.z = acc[i][2] + bias[bn + tx * 4 + 2];
    r.w = acc[i][3] + bias[bn + tx * 4 + 3];
    if (mode == 0) {
      *(float4*)&out[row * 512 + bn + tx * 4] = r;
    } else {
      int bb = row >> 10;
      int tt2 = row & 1023;
      int head = bn >> 6;
      *(float4*)&out[(((bb * NH + head) * TT + tt2) << 6) + tx * 4] = r;
    }
  }
}

__global__ __launch_bounds__(256) void k_gemm(
    const float* __restrict__ A, const float* __restrict__ W,
    const float* __restrict__ bias, float* __restrict__ out, int mode) {
  gemm_body(A, W, bias, out, blockIdx.y * 64, blockIdx.x * 64, mode);
}

__global__ __launch_bounds__(256) void k_gemm_qkv(
    const float* __restrict__ A,
    const float* __restrict__ Wq, const float* __restrict__ bq,
    const float* __restrict__ Wk, const float* __restrict__ bk,
    const float* __restrict__ Wv, const float* __restrict__ bv,
    float* __restrict__ Qf, float* __restrict__ Kf, float* __restrict__ Vf) {
  int which = blockIdx.x >> 3;
  int bn = (blockIdx.x & 7) * 64;
  const float* W = (which == 0) ? Wq : (which == 1) ? Wk : Wv;
  const float* b = (which == 0) ? bq : (which == 1) ? bk : bv;
  float* out = (which == 0) ? Qf : (which == 1) ? Kf : Vf;
  gemm_body(A, W, b, out, blockIdx.y * 64, bn, 1);
}

// ---------------------------------------------------------------------------
// Per-token scalars in fp64 (float4 loads in exact d order; 256 blocks).
// ---------------------------------------------------------------------------
__global__ __launch_bounds__(64) void k_tokscal64(
    const float* __restrict__ Qg, const float* __restrict__ Kg,
    const double* __restrict__ wphid, const float* __restrict__ Wta,
    const float* __restrict__ Wtb, const double* __restrict__ wtaud,
    double4* __restrict__ sqd4, double4* __restrict__ skd4) {
  __shared__ double wp[128], wa[128], wb[128], wt[128];
  int tid = threadIdx.x;
#pragma unroll
  for (int h = 0; h < 2; ++h) {
    int i = h * 64 + tid;
    wp[i] = wphid[i];
    wa[i] = (double)Wta[i];
    wb[i] = (double)Wtb[i];
    wt[i] = wtaud[i];
  }
  __syncthreads();
  int tok = blockIdx.x * 64 + tid;
  const float4* qr = (const float4*)(Qg + (size_t)tok * 64);
  const float4* kr = (const float4*)(Kg + (size_t)tok * 64);
  double sp = 0., sa = 0., sb = 0., st = 0.;
  double kp = 0., ka = 0., kb2 = 0., kt = 0.;
#pragma unroll
  for (int i = 0; i < 16; ++i) {
    float4 qv = qr[i];
    float4 kv = kr[i];
    double q0 = (double)qv.x, q1 = (double)qv.y, q2 = (double)qv.z, q3 = (double)qv.w;
    double k0 = (double)kv.x, k1 = (double)kv.y, k2 = (double)kv.z, k3 = (double)kv.w;
    int d = i * 4;
    sp += q0 * wp[d]; sp += q1 * wp[d + 1]; sp += q2 * wp[d + 2]; sp += q3 * wp[d + 3];
    sa += q0 * wa[d]; sa += q1 * wa[d + 1]; sa += q2 * wa[d + 2]; sa += q3 * wa[d + 3];
    sb += q0 * wb[d]; sb += q1 * wb[d + 1]; sb += q2 * wb[d + 2]; sb += q3 * wb[d + 3];
    st += q0 * wt[d]; st += q1 * wt[d + 1]; st += q2 * wt[d + 2]; st += q3 * wt[d + 3];
    kp += k0 * wp[64 + d]; kp += k1 * wp[64 + d + 1]; kp += k2 * wp[64 + d + 2]; kp += k3 * wp[64 + d + 3];
    ka += k0 * wa[64 + d]; ka += k1 * wa[64 + d + 1]; ka += k2 * wa[64 + d + 2]; ka += k3 * wa[64 + d + 3];
    kb2 += k0 * wb[64 + d]; kb2 += k1 * wb[64 + d + 1]; kb2 += k2 * wb[64 + d + 2]; kb2 += k3 * wb[64 + d + 3];
    kt += k0 * wt[64 + d]; kt += k1 * wt[64 + d + 1]; kt += k2 * wt[64 + d + 2]; kt += k3 * wt[64 + d + 3];
  }
  sqd4[tok] = make_double4(sp, sa, sb, st);
  skd4[tok] = make_double4(kp, ka, kb2, kt);
}

// ---------------------------------------------------------------------------
// Score GEMM + fused per-tile top-16. 128x128 tile, 8x8 register tile, BK=32,
// K-transpose fused into staging; d ascending, one fmaf per d per element —
// bit-identical scores. Epilogue: per query row, top-16 of the tile's 128
// keys by (value desc, GLOBAL index asc) — the union over 8 tiles provably
// contains the global top-16 under the same order. Writes only (val, idx)
// candidates: 16 MB instead of 64 MB of raw scores.
// Grid (8 ktiles, 8 qtiles, 16 bh), 256 threads.
// ---------------------------------------------------------------------------
__global__ __launch_bounds__(256) void k_score_sel(
    const float* __restrict__ Qf, const float* __restrict__ Kf,
    float* __restrict__ CandV, int* __restrict__ CandI) {
  __shared__ float As[32][132];
  __shared__ float Bs[32][132];
  const int bn = blockIdx.x * 128;
  const int bm = blockIdx.y * 128;
  const int bh = blockIdx.z;
  const float* A = Qf + (size_t)bh * (TT * 64);
  const float* K = Kf + (size_t)bh * (TT * 64);
  const int tid = threadIdx.x;
  const int tx = tid & 15;
  const int ty = tid >> 4;
  float acc[8][8];
#pragma unroll
  for (int i = 0; i < 8; ++i)
#pragma unroll
    for (int j = 0; j < 8; ++j) acc[i][j] = 0.f;
  for (int k0 = 0; k0 < 64; k0 += 32) {
#pragma unroll
    for (int i = 0; i < 4; ++i) {
      int idx = i * 256 + tid;
      int row = idx >> 3;
      int c4 = (idx & 7) << 2;
      float4 av = *(const float4*)&A[(size_t)(bm + row) * 64 + k0 + c4];
      As[c4 + 0][row] = av.x;
      As[c4 + 1][row] = av.y;
      As[c4 + 2][row] = av.z;
      As[c4 + 3][row] = av.w;
      float4 kv = *(const float4*)&K[(size_t)(bn + row) * 64 + k0 + c4];
      Bs[c4 + 0][row] = kv.x;
      Bs[c4 + 1][row] = kv.y;
      Bs[c4 + 2][row] = kv.z;
      Bs[c4 + 3][row] = kv.w;
    }
    __syncthreads();
#pragma unroll
    for (int kk = 0; kk < 32; ++kk) {
      float4 alo = *(const float4*)&As[kk][ty * 8];
      float4 ahi = *(const float4*)&As[kk][ty * 8 + 4];
      float4 blo = *(const float4*)&Bs[kk][tx * 8];
      float4 bhi = *(const float4*)&Bs[kk][tx * 8 + 4];
      float a[8] = {alo.x, alo.y, alo.z, alo.w, ahi.x, ahi.y, ahi.z, ahi.w};
      float b[8] = {blo.x, blo.y, blo.z, blo.w, bhi.x, bhi.y, bhi.z, bhi.w};
#pragma unroll
      for (int i = 0; i < 8; ++i)
#pragma unroll
        for (int j = 0; j < 8; ++j)
          acc[i][j] = fmaf(a[i], b[j], acc[i][j]);
    }
    __syncthreads();
  }
  // ---- per-tile top-16 per query row (16-lane ty-group cooperates) ----
  const int t = blockIdx.x;   // tile index 0..7
#pragma unroll 1
  for (int i = 0; i < 8; ++i) {
    float tv[8];
#pragma unroll
    for (int j = 0; j < 8; ++j) tv[j] = acc[i][j];
    float lb = tv[0];
    int lj = 0;
#pragma unroll
    for (int j = 1; j < 8; ++j)
      if (tv[j] > lb) { lb = tv[j]; lj = j; }   // strict > : smaller j (= smaller idx) wins ties
    float wvv = 0.f;
    int wii = 0;
#pragma unroll 1
    for (int it = 0; it < NTOPK; ++it) {
      float bv = lb;
      int bidx = bn + tx * 8 + lj;
#pragma unroll
      for (int off = 8; off >= 1; off >>= 1) {
        float ov = __shfl_xor(bv, off, 64);
        int oi = __shfl_xor(bidx, off, 64);
        if (ov > bv || (ov == bv && oi < bidx)) { bv = ov; bidx = oi; }
      }
      if (tx == it) { wvv = bv; wii = bidx; }
      int rel = bidx - bn;    // 0..127
      if (tx == (rel >> 3)) {
        tv[rel & 7] = -INFINITY;
        lb = tv[0];
        lj = 0;
#pragma unroll
        for (int j = 1; j < 8; ++j)
          if (tv[j] > lb) { lb = tv[j]; lj = j; }
      }
    }
    size_t qg = (size_t)bh * TT + bm + ty * 8 + i;
    CandV[qg * 128 + t * 16 + tx] = wvv;
    CandI[qg * 128 + t * 16 + tx] = wii;
  }
}

// ---------------------------------------------------------------------------
// Top-16 of the 128 candidates (2/lane) + fp32 logits/softmax/attend.
// One WAVE per query. (value desc, index asc) at every compare — selection
// identical to global top-16 of all 1024 scores.
// ---------------------------------------------------------------------------
__global__ __launch_bounds__(256) void k_topk2(
    const float* __restrict__ CandV, const int* __restrict__ CandI,
    const float* __restrict__ Vg, const double4* __restrict__ sqd4,
    const double4* __restrict__ skd4, const double* __restrict__ ccd,
    const float* __restrict__ btaP, const float* __restrict__ btbP,
    float* __restrict__ C) {
  const int tid = threadIdx.x;
  const int lane = tid & 63;
  const int wv = tid >> 6;
  const int qg = blockIdx.x * 4 + wv;   // 0..16383
  const int bh = qg >> 10;
  const int qa = qg & 1023;
  const int bb = bh >> 3;
  const int hh = bh & 7;
  const float* Vbh = Vg + (size_t)bh * (TT * 64);

  float v0 = CandV[(size_t)qg * 128 + lane];
  float v1 = CandV[(size_t)qg * 128 + 64 + lane];
  int i0 = CandI[(size_t)qg * 128 + lane];
  int i1 = CandI[(size_t)qg * 128 + 64 + lane];
  int myk = 0;
#pragma unroll 1
  for (int it = 0; it < NTOPK; ++it) {
    bool f = (v0 > v1) || (v0 == v1 && i0 < i1);
    float bv = f ? v0 : v1;
    int bidx = f ? i0 : i1;
#pragma unroll
    for (int off = 32; off >= 1; off >>= 1) {
      float ov = __shfl_xor(bv, off, 64);
      int oi = __shfl_xor(bidx, off, 64);
      if (ov > bv || (ov == bv && oi < bidx)) { bv = ov; bidx = oi; }
    }
    if (lane == it) myk = bidx;
    if (i0 == bidx) v0 = -INFINITY;
    if (i1 == bidx) v1 = -INFINITY;
  }
  const double cphi = ccd[0];
  const double ctau = ccd[1];
  const double bta0 = (double)btaP[0];
  const double btb0 = (double)btbP[0];
  double4 sq = sqd4[qg];
  float logit = -INFINITY;
  if (lane < 16) {
    double4 sk = skd4[bh * TT + myk];
    float xs = (float)(sq.x + sk.x + cphi);
    float ta = (float)(sq.y + sk.y + bta0);
    float tb = (float)(sq.z + sk.z + btb0);
    float tl = (float)(sq.w + sk.w + ctau);
    float phi = 1.f / (1.f + __expf(-xs));
    float ti = 1.f / (1.f + __expf(-(ta + tb)));          // T_SCALAR = 1
    float tau = fmaxf(tl, 0.f) + log1pf(__expf(-fabsf(tl))) + 1e-6f;
    logit = phi / tau * (1.f - __expf(-tau * ti));
  }
  float m = logit;
#pragma unroll
  for (int off = 8; off >= 1; off >>= 1) m = fmaxf(m, __shfl_xor(m, off, 64));
  float e = (lane < 16) ? __expf(logit - m) : 0.f;
  float ssum = e;
#pragma unroll
  for (int off = 8; off >= 1; off >>= 1) ssum += __shfl_xor(ssum, off, 64);
  float w = e / ssum;
  float outv = 0.f;
#pragma unroll
  for (int k2 = 0; k2 < NTOPK; ++k2) {
    float wk = __shfl(w, k2, 64);
    int ik = __shfl(myk, k2, 64);
    outv = fmaf(wk, Vbh[(size_t)ik * 64 + lane], outv);
  }
  C[(bb * TT + qa) * 512 + hh * 64 + lane] = outv;
}

// ---------------------------------------------------------------------------
// Fallback fused attention (round-5 path) for small workspaces.
// ---------------------------------------------------------------------------
__global__ __launch_bounds__(256) void k_attn(
    const float* __restrict__ Qg, const float* __restrict__ Kg,
    const float* __restrict__ Vg, const double4* __restrict__ sqd4,
    const double4* __restrict__ skd4, const double* __restrict__ ccd,
    const float* __restrict__ btaP, const float* __restrict__ btbP,
    float* __restrict__ C) {
  __shared__ float qs[8][64];
  __shared__ float sc[8][1024];
  const int bh = blockIdx.y;
  const int q0 = blockIdx.x * 8;
  const int tid = threadIdx.x;
  const int lane = tid & 63;
  const int wv = tid >> 6;
  if (tid < 128) {
    int q = tid >> 4, d4 = (tid & 15) << 2;
    *(float4*)&qs[q][d4] = *(const float4*)&Qg[(size_t)(bh * TT + q0 + q) * 64 + d4];
  }
  __syncthreads();
#pragma unroll 1
  for (int c = 0; c < 4; ++c) {
    const int kb = (c * 4 + wv) * 64;
    const float* krow = &Kg[(size_t)(bh * TT + kb + lane) * 64];
    float4 kr[16];
#pragma unroll
    for (int i = 0; i < 16; ++i) kr[i] = *(const float4*)&krow[i * 4];
#pragma unroll
    for (int q = 0; q < 8; ++q) {
      float s = 0.f;
#pragma unroll
      for (int i = 0; i < 16; ++i) {
        float4 q4 = *(const float4*)&qs[q][i * 4];
        s = fmaf(q4.x, kr[i].x, s);
        s = fmaf(q4.y, kr[i].y, s);
        s = fmaf(q4.z, kr[i].z, s);
        s = fmaf(q4.w, kr[i].w, s);
      }
      sc[q][kb + lane] = s;
    }
  }
  __syncthreads();
  const double cphi = ccd[0];
  const double ctau = ccd[1];
  const double bta0 = (double)btaP[0];
  const double btb0 = (double)btbP[0];
  const int bb = bh >> 3;
  const int hh = bh & 7;
  const float* Vbh = Vg + (size_t)bh * (TT * 64);
#pragma unroll 1
  for (int qq = 0; qq < 2; ++qq) {
    const int ql = wv * 2 + qq;
    const int qa = q0 + ql;
    const float* rowp = &sc[ql][0];
    float v[16];
#pragma unroll
    for (int jj = 0; jj < 16; ++jj) v[jj] = rowp[jj * 64 + lane];
    float gv[4];
    int gj[4];
#pragma unroll
    for (int g = 0; g < 4; ++g) {
      gv[g] = v[4 * g];
      gj[g] = 4 * g;
#pragma unroll
      for (int e = 1; e < 4; ++e) {
        if (v[4 * g + e] > gv[g]) { gv[g] = v[4 * g + e]; gj[g] = 4 * g + e; }
      }
    }
    int myk = 0;
#pragma unroll 1
    for (int it = 0; it < NTOPK; ++it) {
      float bvv = gv[0];
      int bjj = gj[0];
#pragma unroll
      for (int g = 1; g < 4; ++g) {
        if (gv[g] > bvv) { bvv = gv[g]; bjj = gj[g]; }
      }
      int bj = bjj * 64 + lane;
#pragma unroll
      for (int off = 32; off >= 1; off >>= 1) {
        float ov = __shfl_xor(bvv, off, 64);
        int oj = __shfl_xor(bj, off, 64);
        if (ov > bvv || (ov == bvv && oj < bj)) { bvv = ov; bj = oj; }
      }
      if (lane == it) myk = bj;
      int owner = bj & 63;
      int slot = bj >> 6;
      if (lane == owner) {
#pragma unroll
        for (int jj = 0; jj < 16; ++jj)
          if (jj == slot) v[jj] = -INFINITY;
        int g2 = slot >> 2;
#pragma unroll
        for (int g = 0; g < 4; ++g) {
          if (g == g2) {
            float ngv = v[4 * g];
            int ngj = 4 * g;
#pragma unroll
            for (int e = 1; e < 4; ++e) {
              if (v[4 * g + e] > ngv) { ngv = v[4 * g + e]; ngj = 4 * g + e; }
            }
            gv[g] = ngv;
            gj[g] = ngj;
          }
        }
      }
    }
    double4 sq = sqd4[bh * TT + qa];
    double logit = -INFINITY;
    if (lane < 16) {
      double4 sk = skd4[bh * TT + myk];
      double phi = 1.0 / (1.0 + exp(-(sq.x + sk.x + cphi)));
      double ta = sq.y + sk.y + bta0;
      double tb = sq.z + sk.z + btb0;
      double ti = 1.0 / (1.0 + exp(-(ta * 1.0 + tb)));
      double tl = sq.w + sk.w + ctau;
      double tau = fmax(tl, 0.0) + log1p(exp(-fabs(tl))) + 1e-6;
      logit = phi / tau * (1.0 - exp(-tau * ti));
    }
    double m = logit;
#pragma unroll
    for (int off = 8; off >= 1; off >>= 1) {
      double om = __shfl_xor(m, off, 64);
      m = fmax(m, om);
    }
    double e = (lane < 16) ? exp(logit - m) : 0.0;
    double ssum = e;
#pragma unroll
    for (int off = 8; off >= 1; off >>= 1) ssum += __shfl_xor(ssum, off, 64);
    double w = e / ssum;
    double outv = 0.0;
#pragma unroll
    for (int k2 = 0; k2 < NTOPK; ++k2) {
      double wk = __shfl(w, k2, 64);
      int ik = __shfl(myk, k2, 64);
      outv += wk * (double)Vbh[(size_t)ik * 64 + lane];
    }
    C[(bb * TT + qa) * 512 + hh * 64 + lane] = (float)outv;
  }
}

// ---------------------------------------------------------------------------
extern "C" void kernel_launch(void* const* d_in, const int* in_sizes, int n_in,
                              void* d_out, int out_size, void* d_ws, size_t ws_size,
                              hipStream_t stream) {
  (void)in_sizes; (void)n_in; (void)out_size;
  const float* x   = (const float*)d_in[0];
  const float* Wq  = (const float*)d_in[1];
  const float* bq  = (const float*)d_in[2];
  const float* Wk  = (const float*)d_in[3];
  const float* bk  = (const float*)d_in[4];
  const float* Wv  = (const float*)d_in[5];
  const float* bv  = (const float*)d_in[6];
  const float* Wo  = (const float*)d_in[7];
  const float* bo  = (const float*)d_in[8];
  const float* Wpi = (const float*)d_in[9];
  const float* bpi = (const float*)d_in[10];
  const float* Wpo = (const float*)d_in[11];
  const float* bpo = (const float*)d_in[12];
  const float* Wta = (const float*)d_in[13];
  const float* bta = (const float*)d_in[14];
  const float* Wtb = (const float*)d_in[15];
  const float* btb = (const float*)d_in[16];
  const float* Wti = (const float*)d_in[17];
  const float* bti = (const float*)d_in[18];
  const float* Wto = (const float*)d_in[19];
  const float* bto = (const float*)d_in[20];

  double* wsd = (double*)d_ws;
  double4* sqd4 = (double4*)wsd;             // 65536 doubles
  double4* skd4 = (double4*)(wsd + 65536);   // 65536 doubles
  double* wphid = wsd + 131072;              // 128
  double* wtaud = wsd + 131200;              // 128
  double* ccd   = wsd + 131328;              // 2 (pad to 131332)
  float* fs = (float*)(wsd + 131332);
  float* Qf = fs;                  // 1,048,576 floats
  float* Kf = fs + 1048576;
  float* Vf = fs + 2097152;
  float* Cf = fs + 3145728;
  float* CandV = fs + 4194304;     // 2,097,152 floats (8 MB)
  int*   CandI = (int*)(fs + 6291456);  // 2,097,152 ints (8 MB)
  const size_t need = (size_t)131332 * 8 + (size_t)(4194304 + 4194304) * 4;

  hipLaunchKernelGGL(k_collapse64, dim3(17), dim3(256), 0, stream,
                     Wpi, bpi, Wpo, bpo, Wti, bti, Wto, bto, wphid, wtaud, ccd);
  hipLaunchKernelGGL(k_gemm_qkv, dim3(24, 32), dim3(256), 0, stream,
                     x, Wq, bq, Wk, bk, Wv, bv, Qf, Kf, Vf);
  hipLaunchKernelGGL(k_tokscal64, dim3(NTOK / 64), dim3(64), 0, stream,
                     Qf, Kf, wphid, Wta, Wtb, wtaud, sqd4, skd4);
  if (ws_size >= need) {
    hipLaunchKernelGGL(k_score_sel, dim3(8, 8, 16), dim3(256), 0, stream,
                       Qf, Kf, CandV, CandI);
    hipLaunchKernelGGL(k_topk2, dim3(NTOK / 4), dim3(256), 0, stream,
                       CandV, CandI, Vf, sqd4, skd4, ccd, bta, btb, Cf);
  } else {
    hipLaunchKernelGGL(k_attn, dim3(TT / 8, NBH), dim3(256), 0, stream,
                       Qf, Kf, Vf, sqd4, skd4, ccd, bta, btb, Cf);
  }
  hipLaunchKernelGGL(k_gemm, dim3(8, 32), dim3(256), 0, stream,
                     Cf, Wo, bo, (float*)d_out, 0);
}

// Round 11
// 371.200 us; speedup vs baseline: 1.0737x; 1.0737x over previous
//
#include <hip/hip_runtime.h>
#include <math.h>

#define BDIM 2
#define TT 1024
#define NH 8
#define HD 64
#define NTOPK 16
#define NBH 16     // BDIM*NH
#define NTOK 16384 // NBH*TT

// ---------------------------------------------------------------------------
// Collapse the linear-linear pair MLPs into 128-dim fp64 vectors.
// ---------------------------------------------------------------------------
__global__ __launch_bounds__(256) void k_collapse64(
    const float* __restrict__ Wpi, const float* __restrict__ bpi,
    const float* __restrict__ Wpo, const float* __restrict__ bpo,
    const float* __restrict__ Wti, const float* __restrict__ bti,
    const float* __restrict__ Wto, const float* __restrict__ bto,
    double* __restrict__ wphid, double* __restrict__ wtaud,
    double* __restrict__ ccd) {
  int tid = threadIdx.x;
  int blk = blockIdx.x;
  if (blk < 16) {
    int r = blk * 16 + (tid >> 4);
    int l = tid & 15;
    double s = 0.;
    if (r < 128) {
      for (int i = 0; i < 32; ++i)
        s += (double)Wpi[r * 512 + l + 16 * i] * (double)Wpo[l + 16 * i];
    } else {
      int rr = r - 128;
      for (int i = 0; i < 16; ++i)
        s += (double)Wti[rr * 256 + l + 16 * i] * (double)Wto[l + 16 * i];
    }
#pragma unroll
    for (int off = 8; off >= 1; off >>= 1) s += __shfl_xor(s, off, 64);
    if (l == 0) {
      if (r < 128) wphid[r] = s;
      else wtaud[r - 128] = s;
    }
  } else {
    int lane = tid & 63;
    if (tid < 64) {
      double p = 0.;
      for (int c = lane; c < 512; c += 64) p += (double)bpi[c] * (double)Wpo[c];
#pragma unroll
      for (int off = 32; off >= 1; off >>= 1) p += __shfl_xor(p, off, 64);
      if (lane == 0) ccd[0] = p + (double)bpo[0];
    } else if (tid < 128) {
      double p = 0.;
      for (int c = lane; c < 256; c += 64) p += (double)bti[c] * (double)Wto[c];
#pragma unroll
      for (int off = 32; off >= 1; off >>= 1) p += __shfl_xor(p, off, 64);
      if (lane == 0) ccd[1] = p + (double)bto[0];
    }
  }
}

// ---------------------------------------------------------------------------
// fp32 GEMM 64x64 tile, BK=32, strict sequential-k fmaf per output element
// (BLAS-order rounding — required for reference-matching top-k selection).
// ---------------------------------------------------------------------------
__device__ __forceinline__ void gemm_body(
    const float* __restrict__ A, const float* __restrict__ W,
    const float* __restrict__ bias, float* __restrict__ out,
    int bm, int bn, int mode) {
  __shared__ float As[32][68];
  __shared__ float Bs[32][64];
  const int tid = threadIdx.x;
  const int tx = tid & 15;
  const int ty = tid >> 4;
  float acc[4][4] = {{0.f, 0.f, 0.f, 0.f}};
  for (int k0 = 0; k0 < 512; k0 += 32) {
#pragma unroll
    for (int i = 0; i < 2; ++i) {
      int idx = i * 256 + tid;
      int row = idx >> 3;
      int c4 = (idx & 7) << 2;
      float4 av = *(const float4*)&A[(bm + row) * 512 + k0 + c4];
      As[c4 + 0][row] = av.x;
      As[c4 + 1][row] = av.y;
      As[c4 + 2][row] = av.z;
      As[c4 + 3][row] = av.w;
    }
#pragma unroll
    for (int i = 0; i < 2; ++i) {
      int idx = i * 256 + tid;
      int br = idx >> 4;
      int bc = (idx & 15) << 2;
      *(float4*)&Bs[br][bc] = *(const float4*)&W[(k0 + br) * 512 + bn + bc];
    }
    __syncthreads();
#pragma unroll
    for (int kk = 0; kk < 32; ++kk) {
      float4 a = *(const float4*)&As[kk][ty * 4];
      float4 b = *(const float4*)&Bs[kk][tx << 2];
      acc[0][0] = fmaf(a.x, b.x, acc[0][0]);
      acc[0][1] = fmaf(a.x, b.y, acc[0][1]);
      acc[0][2] = fmaf(a.x, b.z, acc[0][2]);
      acc[0][3] = fmaf(a.x, b.w, acc[0][3]);
      acc[1][0] = fmaf(a.y, b.x, acc[1][0]);
      acc[1][1] = fmaf(a.y, b.y, acc[1][1]);
      acc[1][2] = fmaf(a.y, b.z, acc[1][2]);
      acc[1][3] = fmaf(a.y, b.w, acc[1][3]);
      acc[2][0] = fmaf(a.z, b.x, acc[2][0]);
      acc[2][1] = fmaf(a.z, b.y, acc[2][1]);
      acc[2][2] = fmaf(a.z, b.z, acc[2][2]);
      acc[2][3] = fmaf(a.z, b.w, acc[2][3]);
      acc[3][0] = fmaf(a.w, b.x, acc[3][0]);
      acc[3][1] = fmaf(a.w, b.y, acc[3][1]);
      acc[3][2] = fmaf(a.w, b.z, acc[3][2]);
      acc[3][3] = fmaf(a.w, b.w, acc[3][3]);
    }
    __syncthreads();
  }
#pragma unroll
  for (int i = 0; i < 4; ++i) {
    int row = bm + ty * 4 + i;
    float4 r;
    r.x = acc[i][0] + bias[bn + tx * 4 + 0];
    r.y = acc[i][1] + bias[bn + tx * 4 + 1];
    r.z = acc[i][2] + bias[bn + tx * 4 + 2];
    r.w = acc[i][3] + bias[bn + tx * 4 + 3];
    if (mode == 0) {
      *(float4*)&out[row * 512 + bn + tx * 4] = r;
    } else {
      int bb = row >> 10;
      int tt2 = row & 1023;
      int head = bn >> 6;
      *(float4*)&out[(((bb * NH + head) * TT + tt2) << 6) + tx * 4] = r;
    }
  }
}

__global__ __launch_bounds__(256) void k_gemm(
    const float* __restrict__ A, const float* __restrict__ W,
    const float* __restrict__ bias, float* __restrict__ out, int mode) {
  gemm_body(A, W, bias, out, blockIdx.y * 64, blockIdx.x * 64, mode);
}

__global__ __launch_bounds__(256) void k_gemm_qkv(
    const float* __restrict__ A,
    const float* __restrict__ Wq, const float* __restrict__ bq,
    const float* __restrict__ Wk, const float* __restrict__ bk,
    const float* __restrict__ Wv, const float* __restrict__ bv,
    float* __restrict__ Qf, float* __restrict__ Kf, float* __restrict__ Vf) {
  int which = blockIdx.x >> 3;
  int bn = (blockIdx.x & 7) * 64;
  const float* W = (which == 0) ? Wq : (which == 1) ? Wk : Wv;
  const float* b = (which == 0) ? bq : (which == 1) ? bk : bv;
  float* out = (which == 0) ? Qf : (which == 1) ? Kf : Vf;
  gemm_body(A, W, b, out, blockIdx.y * 64, bn, 1);
}

// ---------------------------------------------------------------------------
// Per-token scalars in fp64 (float4 loads in exact d order; 256 blocks).
// ---------------------------------------------------------------------------
__global__ __launch_bounds__(64) void k_tokscal64(
    const float* __restrict__ Qg, const float* __restrict__ Kg,
    const double* __restrict__ wphid, const float* __restrict__ Wta,
    const float* __restrict__ Wtb, const double* __restrict__ wtaud,
    double4* __restrict__ sqd4, double4* __restrict__ skd4) {
  __shared__ double wp[128], wa[128], wb[128], wt[128];
  int tid = threadIdx.x;
#pragma unroll
  for (int h = 0; h < 2; ++h) {
    int i = h * 64 + tid;
    wp[i] = wphid[i];
    wa[i] = (double)Wta[i];
    wb[i] = (double)Wtb[i];
    wt[i] = wtaud[i];
  }
  __syncthreads();
  int tok = blockIdx.x * 64 + tid;
  const float4* qr = (const float4*)(Qg + (size_t)tok * 64);
  const float4* kr = (const float4*)(Kg + (size_t)tok * 64);
  double sp = 0., sa = 0., sb = 0., st = 0.;
  double kp = 0., ka = 0., kb2 = 0., kt = 0.;
#pragma unroll
  for (int i = 0; i < 16; ++i) {
    float4 qv = qr[i];
    float4 kv = kr[i];
    double q0 = (double)qv.x, q1 = (double)qv.y, q2 = (double)qv.z, q3 = (double)qv.w;
    double k0 = (double)kv.x, k1 = (double)kv.y, k2 = (double)kv.z, k3 = (double)kv.w;
    int d = i * 4;
    sp += q0 * wp[d]; sp += q1 * wp[d + 1]; sp += q2 * wp[d + 2]; sp += q3 * wp[d + 3];
    sa += q0 * wa[d]; sa += q1 * wa[d + 1]; sa += q2 * wa[d + 2]; sa += q3 * wa[d + 3];
    sb += q0 * wb[d]; sb += q1 * wb[d + 1]; sb += q2 * wb[d + 2]; sb += q3 * wb[d + 3];
    st += q0 * wt[d]; st += q1 * wt[d + 1]; st += q2 * wt[d + 2]; st += q3 * wt[d + 3];
    kp += k0 * wp[64 + d]; kp += k1 * wp[64 + d + 1]; kp += k2 * wp[64 + d + 2]; kp += k3 * wp[64 + d + 3];
    ka += k0 * wa[64 + d]; ka += k1 * wa[64 + d + 1]; ka += k2 * wa[64 + d + 2]; ka += k3 * wa[64 + d + 3];
    kb2 += k0 * wb[64 + d]; kb2 += k1 * wb[64 + d + 1]; kb2 += k2 * wb[64 + d + 2]; kb2 += k3 * wb[64 + d + 3];
    kt += k0 * wt[64 + d]; kt += k1 * wt[64 + d + 1]; kt += k2 * wt[64 + d + 2]; kt += k3 * wt[64 + d + 3];
  }
  sqd4[tok] = make_double4(sp, sa, sb, st);
  skd4[tok] = make_double4(kp, ka, kb2, kt);
}

// ---------------------------------------------------------------------------
// Score GEMM + fused per-tile top-16, SPILL-FREE epilogue: row loop fully
// unrolled (static acc indices), per-thread scores held in scalars t0..t7,
// knockout via predicated static chain. Selection semantics identical to
// round 10 (value desc, global index asc) — union of 8 per-tile top-16s
// contains the global top-16 under the same total order.
// Grid (8 ktiles, 8 qtiles, 16 bh), 256 threads.
// ---------------------------------------------------------------------------
__global__ __launch_bounds__(256) void k_score_sel(
    const float* __restrict__ Qf, const float* __restrict__ Kf,
    float* __restrict__ CandV, int* __restrict__ CandI) {
  __shared__ float As[32][132];
  __shared__ float Bs[32][132];
  const int bn = blockIdx.x * 128;
  const int bm = blockIdx.y * 128;
  const int bh = blockIdx.z;
  const float* A = Qf + (size_t)bh * (TT * 64);
  const float* K = Kf + (size_t)bh * (TT * 64);
  const int tid = threadIdx.x;
  const int tx = tid & 15;
  const int ty = tid >> 4;
  float acc[8][8];
#pragma unroll
  for (int i = 0; i < 8; ++i)
#pragma unroll
    for (int j = 0; j < 8; ++j) acc[i][j] = 0.f;
  for (int k0 = 0; k0 < 64; k0 += 32) {
#pragma unroll
    for (int i = 0; i < 4; ++i) {
      int idx = i * 256 + tid;
      int row = idx >> 3;
      int c4 = (idx & 7) << 2;
      float4 av = *(const float4*)&A[(size_t)(bm + row) * 64 + k0 + c4];
      As[c4 + 0][row] = av.x;
      As[c4 + 1][row] = av.y;
      As[c4 + 2][row] = av.z;
      As[c4 + 3][row] = av.w;
      float4 kv = *(const float4*)&K[(size_t)(bn + row) * 64 + k0 + c4];
      Bs[c4 + 0][row] = kv.x;
      Bs[c4 + 1][row] = kv.y;
      Bs[c4 + 2][row] = kv.z;
      Bs[c4 + 3][row] = kv.w;
    }
    __syncthreads();
#pragma unroll
    for (int kk = 0; kk < 32; ++kk) {
      float4 alo = *(const float4*)&As[kk][ty * 8];
      float4 ahi = *(const float4*)&As[kk][ty * 8 + 4];
      float4 blo = *(const float4*)&Bs[kk][tx * 8];
      float4 bhi = *(const float4*)&Bs[kk][tx * 8 + 4];
      float a[8] = {alo.x, alo.y, alo.z, alo.w, ahi.x, ahi.y, ahi.z, ahi.w};
      float b[8] = {blo.x, blo.y, blo.z, blo.w, bhi.x, bhi.y, bhi.z, bhi.w};
#pragma unroll
      for (int i = 0; i < 8; ++i)
#pragma unroll
        for (int j = 0; j < 8; ++j)
          acc[i][j] = fmaf(a[i], b[j], acc[i][j]);
    }
    __syncthreads();
  }
  // ---- per-tile top-16 per query row — scalars only, no dynamic indexing --
  const int t = blockIdx.x;   // tile index 0..7
#pragma unroll
  for (int i = 0; i < 8; ++i) {
    float t0 = acc[i][0], t1 = acc[i][1], t2 = acc[i][2], t3 = acc[i][3];
    float t4 = acc[i][4], t5 = acc[i][5], t6 = acc[i][6], t7 = acc[i][7];
    float wvv = 0.f;
    int wii = 0;
#pragma unroll 1
    for (int it = 0; it < NTOPK; ++it) {
      float lb = t0;
      int lj = 0;
      if (t1 > lb) { lb = t1; lj = 1; }   // strict > : lowest j (lowest idx) wins ties
      if (t2 > lb) { lb = t2; lj = 2; }
      if (t3 > lb) { lb = t3; lj = 3; }
      if (t4 > lb) { lb = t4; lj = 4; }
      if (t5 > lb) { lb = t5; lj = 5; }
      if (t6 > lb) { lb = t6; lj = 6; }
      if (t7 > lb) { lb = t7; lj = 7; }
      float bv = lb;
      int bidx = bn + tx * 8 + lj;
#pragma unroll
      for (int off = 8; off >= 1; off >>= 1) {
        float ov = __shfl_xor(bv, off, 64);
        int oi = __shfl_xor(bidx, off, 64);
        if (ov > bv || (ov == bv && oi < bidx)) { bv = ov; bidx = oi; }
      }
      if (tx == it) { wvv = bv; wii = bidx; }
      int rel = bidx - bn;    // 0..127
      bool mine = (tx == (rel >> 3));
      int s = rel & 7;
      t0 = (mine && s == 0) ? -INFINITY : t0;
      t1 = (mine && s == 1) ? -INFINITY : t1;
      t2 = (mine && s == 2) ? -INFINITY : t2;
      t3 = (mine && s == 3) ? -INFINITY : t3;
      t4 = (mine && s == 4) ? -INFINITY : t4;
      t5 = (mine && s == 5) ? -INFINITY : t5;
      t6 = (mine && s == 6) ? -INFINITY : t6;
      t7 = (mine && s == 7) ? -INFINITY : t7;
    }
    size_t qg = (size_t)bh * TT + bm + ty * 8 + i;
    CandV[qg * 128 + t * 16 + tx] = wvv;
    CandI[qg * 128 + t * 16 + tx] = wii;
  }
}

// ---------------------------------------------------------------------------
// Top-16 of the 128 candidates (2/lane) + fp32 logits/softmax/attend.
// One WAVE per query. (value desc, index asc) at every compare.
// ---------------------------------------------------------------------------
__global__ __launch_bounds__(256) void k_topk2(
    const float* __restrict__ CandV, const int* __restrict__ CandI,
    const float* __restrict__ Vg, const double4* __restrict__ sqd4,
    const double4* __restrict__ skd4, const double* __restrict__ ccd,
    const float* __restrict__ btaP, const float* __restrict__ btbP,
    float* __restrict__ C) {
  const int tid = threadIdx.x;
  const int lane = tid & 63;
  const int wv = tid >> 6;
  const int qg = blockIdx.x * 4 + wv;   // 0..16383
  const int bh = qg >> 10;
  const int qa = qg & 1023;
  const int bb = bh >> 3;
  const int hh = bh & 7;
  const float* Vbh = Vg + (size_t)bh * (TT * 64);

  float v0 = CandV[(size_t)qg * 128 + lane];
  float v1 = CandV[(size_t)qg * 128 + 64 + lane];
  int i0 = CandI[(size_t)qg * 128 + lane];
  int i1 = CandI[(size_t)qg * 128 + 64 + lane];
  int myk = 0;
#pragma unroll 1
  for (int it = 0; it < NTOPK; ++it) {
    bool f = (v0 > v1) || (v0 == v1 && i0 < i1);
    float bv = f ? v0 : v1;
    int bidx = f ? i0 : i1;
#pragma unroll
    for (int off = 32; off >= 1; off >>= 1) {
      float ov = __shfl_xor(bv, off, 64);
      int oi = __shfl_xor(bidx, off, 64);
      if (ov > bv || (ov == bv && oi < bidx)) { bv = ov; bidx = oi; }
    }
    if (lane == it) myk = bidx;
    if (i0 == bidx) v0 = -INFINITY;
    if (i1 == bidx) v1 = -INFINITY;
  }
  const double cphi = ccd[0];
  const double ctau = ccd[1];
  const double bta0 = (double)btaP[0];
  const double btb0 = (double)btbP[0];
  double4 sq = sqd4[qg];
  float logit = -INFINITY;
  if (lane < 16) {
    double4 sk = skd4[bh * TT + myk];
    float xs = (float)(sq.x + sk.x + cphi);
    float ta = (float)(sq.y + sk.y + bta0);
    float tb = (float)(sq.z + sk.z + btb0);
    float tl = (float)(sq.w + sk.w + ctau);
    float phi = 1.f / (1.f + __expf(-xs));
    float ti = 1.f / (1.f + __expf(-(ta + tb)));          // T_SCALAR = 1
    float tau = fmaxf(tl, 0.f) + log1pf(__expf(-fabsf(tl))) + 1e-6f;
    logit = phi / tau * (1.f - __expf(-tau * ti));
  }
  float m = logit;
#pragma unroll
  for (int off = 8; off >= 1; off >>= 1) m = fmaxf(m, __shfl_xor(m, off, 64));
  float e = (lane < 16) ? __expf(logit - m) : 0.f;
  float ssum = e;
#pragma unroll
  for (int off = 8; off >= 1; off >>= 1) ssum += __shfl_xor(ssum, off, 64);
  float w = e / ssum;
  float outv = 0.f;
#pragma unroll
  for (int k2 = 0; k2 < NTOPK; ++k2) {
    float wk = __shfl(w, k2, 64);
    int ik = __shfl(myk, k2, 64);
    outv = fmaf(wk, Vbh[(size_t)ik * 64 + lane], outv);
  }
  C[(bb * TT + qa) * 512 + hh * 64 + lane] = outv;
}

// ---------------------------------------------------------------------------
// Fallback fused attention (round-5 path) for small workspaces.
// ---------------------------------------------------------------------------
__global__ __launch_bounds__(256) void k_attn(
    const float* __restrict__ Qg, const float* __restrict__ Kg,
    const float* __restrict__ Vg, const double4* __restrict__ sqd4,
    const double4* __restrict__ skd4, const double* __restrict__ ccd,
    const float* __restrict__ btaP, const float* __restrict__ btbP,
    float* __restrict__ C) {
  __shared__ float qs[8][64];
  __shared__ float sc[8][1024];
  const int bh = blockIdx.y;
  const int q0 = blockIdx.x * 8;
  const int tid = threadIdx.x;
  const int lane = tid & 63;
  const int wv = tid >> 6;
  if (tid < 128) {
    int q = tid >> 4, d4 = (tid & 15) << 2;
    *(float4*)&qs[q][d4] = *(const float4*)&Qg[(size_t)(bh * TT + q0 + q) * 64 + d4];
  }
  __syncthreads();
#pragma unroll 1
  for (int c = 0; c < 4; ++c) {
    const int kb = (c * 4 + wv) * 64;
    const float* krow = &Kg[(size_t)(bh * TT + kb + lane) * 64];
    float4 kr[16];
#pragma unroll
    for (int i = 0; i < 16; ++i) kr[i] = *(const float4*)&krow[i * 4];
#pragma unroll
    for (int q = 0; q < 8; ++q) {
      float s = 0.f;
#pragma unroll
      for (int i = 0; i < 16; ++i) {
        float4 q4 = *(const float4*)&qs[q][i * 4];
        s = fmaf(q4.x, kr[i].x, s);
        s = fmaf(q4.y, kr[i].y, s);
        s = fmaf(q4.z, kr[i].z, s);
        s = fmaf(q4.w, kr[i].w, s);
      }
      sc[q][kb + lane] = s;
    }
  }
  __syncthreads();
  const double cphi = ccd[0];
  const double ctau = ccd[1];
  const double bta0 = (double)btaP[0];
  const double btb0 = (double)btbP[0];
  const int bb = bh >> 3;
  const int hh = bh & 7;
  const float* Vbh = Vg + (size_t)bh * (TT * 64);
#pragma unroll 1
  for (int qq = 0; qq < 2; ++qq) {
    const int ql = wv * 2 + qq;
    const int qa = q0 + ql;
    const float* rowp = &sc[ql][0];
    float v[16];
#pragma unroll
    for (int jj = 0; jj < 16; ++jj) v[jj] = rowp[jj * 64 + lane];
    float gv[4];
    int gj[4];
#pragma unroll
    for (int g = 0; g < 4; ++g) {
      gv[g] = v[4 * g];
      gj[g] = 4 * g;
#pragma unroll
      for (int e = 1; e < 4; ++e) {
        if (v[4 * g + e] > gv[g]) { gv[g] = v[4 * g + e]; gj[g] = 4 * g + e; }
      }
    }
    int myk = 0;
#pragma unroll 1
    for (int it = 0; it < NTOPK; ++it) {
      float bvv = gv[0];
      int bjj = gj[0];
#pragma unroll
      for (int g = 1; g < 4; ++g) {
        if (gv[g] > bvv) { bvv = gv[g]; bjj = gj[g]; }
      }
      int bj = bjj * 64 + lane;
#pragma unroll
      for (int off = 32; off >= 1; off >>= 1) {
        float ov = __shfl_xor(bvv, off, 64);
        int oj = __shfl_xor(bj, off, 64);
        if (ov > bvv || (ov == bvv && oj < bj)) { bvv = ov; bj = oj; }
      }
      if (lane == it) myk = bj;
      int owner = bj & 63;
      int slot = bj >> 6;
      if (lane == owner) {
#pragma unroll
        for (int jj = 0; jj < 16; ++jj)
          if (jj == slot) v[jj] = -INFINITY;
        int g2 = slot >> 2;
#pragma unroll
        for (int g = 0; g < 4; ++g) {
          if (g == g2) {
            float ngv = v[4 * g];
            int ngj = 4 * g;
#pragma unroll
            for (int e = 1; e < 4; ++e) {
              if (v[4 * g + e] > ngv) { ngv = v[4 * g + e]; ngj = 4 * g + e; }
            }
            gv[g] = ngv;
            gj[g] = ngj;
          }
        }
      }
    }
    double4 sq = sqd4[bh * TT + qa];
    double logit = -INFINITY;
    if (lane < 16) {
      double4 sk = skd4[bh * TT + myk];
      double phi = 1.0 / (1.0 + exp(-(sq.x + sk.x + cphi)));
      double ta = sq.y + sk.y + bta0;
      double tb = sq.z + sk.z + btb0;
      double ti = 1.0 / (1.0 + exp(-(ta * 1.0 + tb)));
      double tl = sq.w + sk.w + ctau;
      double tau = fmax(tl, 0.0) + log1p(exp(-fabs(tl))) + 1e-6;
      logit = phi / tau * (1.0 - exp(-tau * ti));
    }
    double m = logit;
#pragma unroll
    for (int off = 8; off >= 1; off >>= 1) {
      double om = __shfl_xor(m, off, 64);
      m = fmax(m, om);
    }
    double e = (lane < 16) ? exp(logit - m) : 0.0;
    double ssum = e;
#pragma unroll
    for (int off = 8; off >= 1; off >>= 1) ssum += __shfl_xor(ssum, off, 64);
    double w = e / ssum;
    double outv = 0.0;
#pragma unroll
    for (int k2 = 0; k2 < NTOPK; ++k2) {
      double wk = __shfl(w, k2, 64);
      int ik = __shfl(myk, k2, 64);
      outv += wk * (double)Vbh[(size_t)ik * 64 + lane];
    }
    C[(bb * TT + qa) * 512 + hh * 64 + lane] = (float)outv;
  }
}

// ---------------------------------------------------------------------------
extern "C" void kernel_launch(void* const* d_in, const int* in_sizes, int n_in,
                              void* d_out, int out_size, void* d_ws, size_t ws_size,
                              hipStream_t stream) {
  (void)in_sizes; (void)n_in; (void)out_size;
  const float* x   = (const float*)d_in[0];
  const float* Wq  = (const float*)d_in[1];
  const float* bq  = (const float*)d_in[2];
  const float* Wk  = (const float*)d_in[3];
  const float* bk  = (const float*)d_in[4];
  const float* Wv  = (const float*)d_in[5];
  const float* bv  = (const float*)d_in[6];
  const float* Wo  = (const float*)d_in[7];
  const float* bo  = (const float*)d_in[8];
  const float* Wpi = (const float*)d_in[9];
  const float* bpi = (const float*)d_in[10];
  const float* Wpo = (const float*)d_in[11];
  const float* bpo = (const float*)d_in[12];
  const float* Wta = (const float*)d_in[13];
  const float* bta = (const float*)d_in[14];
  const float* Wtb = (const float*)d_in[15];
  const float* btb = (const float*)d_in[16];
  const float* Wti = (const float*)d_in[17];
  const float* bti = (const float*)d_in[18];
  const float* Wto = (const float*)d_in[19];
  const float* bto = (const float*)d_in[20];

  double* wsd = (double*)d_ws;
  double4* sqd4 = (double4*)wsd;             // 65536 doubles
  double4* skd4 = (double4*)(wsd + 65536);   // 65536 doubles
  double* wphid = wsd + 131072;              // 128
  double* wtaud = wsd + 131200;              // 128
  double* ccd   = wsd + 131328;              // 2 (pad to 131332)
  float* fs = (float*)(wsd + 131332);
  float* Qf = fs;                  // 1,048,576 floats
  float* Kf = fs + 1048576;
  float* Vf = fs + 2097152;
  float* Cf = fs + 3145728;
  float* CandV = fs + 4194304;     // 2,097,152 floats (8 MB)
  int*   CandI = (int*)(fs + 6291456);  // 2,097,152 ints (8 MB)
  const size_t need = (size_t)131332 * 8 + (size_t)(4194304 + 4194304) * 4;

  hipLaunchKernelGGL(k_collapse64, dim3(17), dim3(256), 0, stream,
                     Wpi, bpi, Wpo, bpo, Wti, bti, Wto, bto, wphid, wtaud, ccd);
  hipLaunchKernelGGL(k_gemm_qkv, dim3(24, 32), dim3(256), 0, stream,
                     x, Wq, bq, Wk, bk, Wv, bv, Qf, Kf, Vf);
  hipLaunchKernelGGL(k_tokscal64, dim3(NTOK / 64), dim3(64), 0, stream,
                     Qf, Kf, wphid, Wta, Wtb, wtaud, sqd4, skd4);
  if (ws_size >= need) {
    hipLaunchKernelGGL(k_score_sel, dim3(8, 8, 16), dim3(256), 0, stream,
                       Qf, Kf, CandV, CandI);
    hipLaunchKernelGGL(k_topk2, dim3(NTOK / 4), dim3(256), 0, stream,
                       CandV, CandI, Vf, sqd4, skd4, ccd, bta, btb, Cf);
  } else {
    hipLaunchKernelGGL(k_attn, dim3(TT / 8, NBH), dim3(256), 0, stream,
                       Qf, Kf, Vf, sqd4, skd4, ccd, bta, btb, Cf);
  }
  hipLaunchKernelGGL(k_gemm, dim3(8, 32), dim3(256), 0, stream,
                     Cf, Wo, bo, (float*)d_out, 0);
}

// Round 12
// 274.429 us; speedup vs baseline: 1.4523x; 1.3526x over previous
//
#include <hip/hip_runtime.h>
#include <math.h>

#define BDIM 2
#define TT 1024
#define NH 8
#define HD 64
#define NTOPK 16
#define NBH 16     // BDIM*NH
#define NTOK 16384 // NBH*TT

// ---------------------------------------------------------------------------
// Collapse the linear-linear pair MLPs into 128-dim fp64 vectors.
// ---------------------------------------------------------------------------
__global__ __launch_bounds__(256) void k_collapse64(
    const float* __restrict__ Wpi, const float* __restrict__ bpi,
    const float* __restrict__ Wpo, const float* __restrict__ bpo,
    const float* __restrict__ Wti, const float* __restrict__ bti,
    const float* __restrict__ Wto, const float* __restrict__ bto,
    double* __restrict__ wphid, double* __restrict__ wtaud,
    double* __restrict__ ccd) {
  int tid = threadIdx.x;
  int blk = blockIdx.x;
  if (blk < 16) {
    int r = blk * 16 + (tid >> 4);
    int l = tid & 15;
    double s = 0.;
    if (r < 128) {
      for (int i = 0; i < 32; ++i)
        s += (double)Wpi[r * 512 + l + 16 * i] * (double)Wpo[l + 16 * i];
    } else {
      int rr = r - 128;
      for (int i = 0; i < 16; ++i)
        s += (double)Wti[rr * 256 + l + 16 * i] * (double)Wto[l + 16 * i];
    }
#pragma unroll
    for (int off = 8; off >= 1; off >>= 1) s += __shfl_xor(s, off, 64);
    if (l == 0) {
      if (r < 128) wphid[r] = s;
      else wtaud[r - 128] = s;
    }
  } else {
    int lane = tid & 63;
    if (tid < 64) {
      double p = 0.;
      for (int c = lane; c < 512; c += 64) p += (double)bpi[c] * (double)Wpo[c];
#pragma unroll
      for (int off = 32; off >= 1; off >>= 1) p += __shfl_xor(p, off, 64);
      if (lane == 0) ccd[0] = p + (double)bpo[0];
    } else if (tid < 128) {
      double p = 0.;
      for (int c = lane; c < 256; c += 64) p += (double)bti[c] * (double)Wto[c];
#pragma unroll
      for (int off = 32; off >= 1; off >>= 1) p += __shfl_xor(p, off, 64);
      if (lane == 0) ccd[1] = p + (double)bto[0];
    }
  }
}

// ---------------------------------------------------------------------------
// fp32 GEMM 64x64 tile, BK=64 (half the barriers of BK=32), strict
// sequential-k fmaf per output element (BLAS-order rounding — required for
// reference-matching top-k selection). k order 0..511 ascending -> bit-exact.
// ---------------------------------------------------------------------------
__device__ __forceinline__ void gemm_body(
    const float* __restrict__ A, const float* __restrict__ W,
    const float* __restrict__ bias, float* __restrict__ out,
    int bm, int bn, int mode) {
  __shared__ float As[64][68];
  __shared__ float Bs[64][64];
  const int tid = threadIdx.x;
  const int tx = tid & 15;
  const int ty = tid >> 4;
  float acc[4][4] = {{0.f, 0.f, 0.f, 0.f}};
  for (int k0 = 0; k0 < 512; k0 += 64) {
#pragma unroll
    for (int i = 0; i < 4; ++i) {
      int idx = i * 256 + tid;     // 0..1023
      int row = idx >> 4;          // 0..63
      int c4 = (idx & 15) << 2;    // 0..60
      float4 av = *(const float4*)&A[(bm + row) * 512 + k0 + c4];
      As[c4 + 0][row] = av.x;
      As[c4 + 1][row] = av.y;
      As[c4 + 2][row] = av.z;
      As[c4 + 3][row] = av.w;
    }
#pragma unroll
    for (int i = 0; i < 4; ++i) {
      int idx = i * 256 + tid;     // 0..1023
      int br = idx >> 4;           // 0..63
      int bc = (idx & 15) << 2;    // 0..60
      *(float4*)&Bs[br][bc] = *(const float4*)&W[(k0 + br) * 512 + bn + bc];
    }
    __syncthreads();
#pragma unroll
    for (int kk = 0; kk < 64; ++kk) {
      float4 a = *(const float4*)&As[kk][ty * 4];
      float4 b = *(const float4*)&Bs[kk][tx << 2];
      acc[0][0] = fmaf(a.x, b.x, acc[0][0]);
      acc[0][1] = fmaf(a.x, b.y, acc[0][1]);
      acc[0][2] = fmaf(a.x, b.z, acc[0][2]);
      acc[0][3] = fmaf(a.x, b.w, acc[0][3]);
      acc[1][0] = fmaf(a.y, b.x, acc[1][0]);
      acc[1][1] = fmaf(a.y, b.y, acc[1][1]);
      acc[1][2] = fmaf(a.y, b.z, acc[1][2]);
      acc[1][3] = fmaf(a.y, b.w, acc[1][3]);
      acc[2][0] = fmaf(a.z, b.x, acc[2][0]);
      acc[2][1] = fmaf(a.z, b.y, acc[2][1]);
      acc[2][2] = fmaf(a.z, b.z, acc[2][2]);
      acc[2][3] = fmaf(a.z, b.w, acc[2][3]);
      acc[3][0] = fmaf(a.w, b.x, acc[3][0]);
      acc[3][1] = fmaf(a.w, b.y, acc[3][1]);
      acc[3][2] = fmaf(a.w, b.z, acc[3][2]);
      acc[3][3] = fmaf(a.w, b.w, acc[3][3]);
    }
    __syncthreads();
  }
#pragma unroll
  for (int i = 0; i < 4; ++i) {
    int row = bm + ty * 4 + i;
    float4 r;
    r.x = acc[i][0] + bias[bn + tx * 4 + 0];
    r.y = acc[i][1] + bias[bn + tx * 4 + 1];
    r.z = acc[i][2] + bias[bn + tx * 4 + 2];
    r.w = acc[i][3] + bias[bn + tx * 4 + 3];
    if (mode == 0) {
      *(float4*)&out[row * 512 + bn + tx * 4] = r;
    } else {
      int bb = row >> 10;
      int tt2 = row & 1023;
      int head = bn >> 6;
      *(float4*)&out[(((bb * NH + head) * TT + tt2) << 6) + tx * 4] = r;
    }
  }
}

__global__ __launch_bounds__(256) void k_gemm(
    const float* __restrict__ A, const float* __restrict__ W,
    const float* __restrict__ bias, float* __restrict__ out, int mode) {
  gemm_body(A, W, bias, out, blockIdx.y * 64, blockIdx.x * 64, mode);
}

__global__ __launch_bounds__(256) void k_gemm_qkv(
    const float* __restrict__ A,
    const float* __restrict__ Wq, const float* __restrict__ bq,
    const float* __restrict__ Wk, const float* __restrict__ bk,
    const float* __restrict__ Wv, const float* __restrict__ bv,
    float* __restrict__ Qf, float* __restrict__ Kf, float* __restrict__ Vf) {
  int which = blockIdx.x >> 3;
  int bn = (blockIdx.x & 7) * 64;
  const float* W = (which == 0) ? Wq : (which == 1) ? Wk : Wv;
  const float* b = (which == 0) ? bq : (which == 1) ? bk : bv;
  float* out = (which == 0) ? Qf : (which == 1) ? Kf : Vf;
  gemm_body(A, W, b, out, blockIdx.y * 64, bn, 1);
}

// ---------------------------------------------------------------------------
// Per-token scalars in fp64 (float4 loads in exact d order; 256 blocks).
// ---------------------------------------------------------------------------
__global__ __launch_bounds__(64) void k_tokscal64(
    const float* __restrict__ Qg, const float* __restrict__ Kg,
    const double* __restrict__ wphid, const float* __restrict__ Wta,
    const float* __restrict__ Wtb, const double* __restrict__ wtaud,
    double4* __restrict__ sqd4, double4* __restrict__ skd4) {
  __shared__ double wp[128], wa[128], wb[128], wt[128];
  int tid = threadIdx.x;
#pragma unroll
  for (int h = 0; h < 2; ++h) {
    int i = h * 64 + tid;
    wp[i] = wphid[i];
    wa[i] = (double)Wta[i];
    wb[i] = (double)Wtb[i];
    wt[i] = wtaud[i];
  }
  __syncthreads();
  int tok = blockIdx.x * 64 + tid;
  const float4* qr = (const float4*)(Qg + (size_t)tok * 64);
  const float4* kr = (const float4*)(Kg + (size_t)tok * 64);
  double sp = 0., sa = 0., sb = 0., st = 0.;
  double kp = 0., ka = 0., kb2 = 0., kt = 0.;
#pragma unroll
  for (int i = 0; i < 16; ++i) {
    float4 qv = qr[i];
    float4 kv = kr[i];
    double q0 = (double)qv.x, q1 = (double)qv.y, q2 = (double)qv.z, q3 = (double)qv.w;
    double k0 = (double)kv.x, k1 = (double)kv.y, k2 = (double)kv.z, k3 = (double)kv.w;
    int d = i * 4;
    sp += q0 * wp[d]; sp += q1 * wp[d + 1]; sp += q2 * wp[d + 2]; sp += q3 * wp[d + 3];
    sa += q0 * wa[d]; sa += q1 * wa[d + 1]; sa += q2 * wa[d + 2]; sa += q3 * wa[d + 3];
    sb += q0 * wb[d]; sb += q1 * wb[d + 1]; sb += q2 * wb[d + 2]; sb += q3 * wb[d + 3];
    st += q0 * wt[d]; st += q1 * wt[d + 1]; st += q2 * wt[d + 2]; st += q3 * wt[d + 3];
    kp += k0 * wp[64 + d]; kp += k1 * wp[64 + d + 1]; kp += k2 * wp[64 + d + 2]; kp += k3 * wp[64 + d + 3];
    ka += k0 * wa[64 + d]; ka += k1 * wa[64 + d + 1]; ka += k2 * wa[64 + d + 2]; ka += k3 * wa[64 + d + 3];
    kb2 += k0 * wb[64 + d]; kb2 += k1 * wb[64 + d + 1]; kb2 += k2 * wb[64 + d + 2]; kb2 += k3 * wb[64 + d + 3];
    kt += k0 * wt[64 + d]; kt += k1 * wt[64 + d + 1]; kt += k2 * wt[64 + d + 2]; kt += k3 * wt[64 + d + 3];
  }
  sqd4[tok] = make_double4(sp, sa, sb, st);
  skd4[tok] = make_double4(kp, ka, kb2, kt);
}

// ---------------------------------------------------------------------------
// Score GEMM (r8 version): Sc[bh][q][k] = sum_d Qf[bh][q][d]*Kf[bh][k][d].
// 128x128 tile, 8x8 register tile, BK=32, fused K-transpose staging.
// d ascending, one fmaf per d per element — bit-identical rounding.
// ---------------------------------------------------------------------------
__global__ __launch_bounds__(256) void k_score(
    const float* __restrict__ Qf, const float* __restrict__ Kf,
    float* __restrict__ Sc) {
  __shared__ float As[32][132];
  __shared__ float Bs[32][132];
  const int bn = blockIdx.x * 128;
  const int bm = blockIdx.y * 128;
  const int bh = blockIdx.z;
  const float* A = Qf + (size_t)bh * (TT * 64);
  const float* K = Kf + (size_t)bh * (TT * 64);
  float* out = Sc + (size_t)bh * (TT * 1024);
  const int tid = threadIdx.x;
  const int tx = tid & 15;
  const int ty = tid >> 4;
  float acc[8][8];
#pragma unroll
  for (int i = 0; i < 8; ++i)
#pragma unroll
    for (int j = 0; j < 8; ++j) acc[i][j] = 0.f;
  for (int k0 = 0; k0 < 64; k0 += 32) {
#pragma unroll
    for (int i = 0; i < 4; ++i) {
      int idx = i * 256 + tid;
      int row = idx >> 3;
      int c4 = (idx & 7) << 2;
      float4 av = *(const float4*)&A[(size_t)(bm + row) * 64 + k0 + c4];
      As[c4 + 0][row] = av.x;
      As[c4 + 1][row] = av.y;
      As[c4 + 2][row] = av.z;
      As[c4 + 3][row] = av.w;
      float4 kv = *(const float4*)&K[(size_t)(bn + row) * 64 + k0 + c4];
      Bs[c4 + 0][row] = kv.x;
      Bs[c4 + 1][row] = kv.y;
      Bs[c4 + 2][row] = kv.z;
      Bs[c4 + 3][row] = kv.w;
    }
    __syncthreads();
#pragma unroll
    for (int kk = 0; kk < 32; ++kk) {
      float4 alo = *(const float4*)&As[kk][ty * 8];
      float4 ahi = *(const float4*)&As[kk][ty * 8 + 4];
      float4 blo = *(const float4*)&Bs[kk][tx * 8];
      float4 bhi = *(const float4*)&Bs[kk][tx * 8 + 4];
      float a[8] = {alo.x, alo.y, alo.z, alo.w, ahi.x, ahi.y, ahi.z, ahi.w};
      float b[8] = {blo.x, blo.y, blo.z, blo.w, bhi.x, bhi.y, bhi.z, bhi.w};
#pragma unroll
      for (int i = 0; i < 8; ++i)
#pragma unroll
        for (int j = 0; j < 8; ++j)
          acc[i][j] = fmaf(a[i], b[j], acc[i][j]);
    }
    __syncthreads();
  }
#pragma unroll
  for (int i = 0; i < 8; ++i) {
    float4 r0 = make_float4(acc[i][0], acc[i][1], acc[i][2], acc[i][3]);
    float4 r1 = make_float4(acc[i][4], acc[i][5], acc[i][6], acc[i][7]);
    size_t base = (size_t)(bm + ty * 8 + i) * 1024 + bn + tx * 8;
    *(float4*)&out[base] = r0;
    *(float4*)&out[base + 4] = r1;
  }
}

// ---------------------------------------------------------------------------
// Top-16 + fp32 logits/softmax/attend. TWO queries per wave (adjacent, same
// bh) with interleaved independent ladders — doubles ILP on the dependent
// shuffle chains. Per-query compare order identical to r8 -> bit-exact
// selection. Candidate slot s of lane maps to key (s>>2)*256 + lane*4 + (s&3).
// ---------------------------------------------------------------------------
__global__ __launch_bounds__(256) void k_topk(
    const float* __restrict__ Sc, const float* __restrict__ Vg,
    const double4* __restrict__ sqd4, const double4* __restrict__ skd4,
    const double* __restrict__ ccd, const float* __restrict__ btaP,
    const float* __restrict__ btbP, float* __restrict__ C) {
  const int tid = threadIdx.x;
  const int lane = tid & 63;
  const int wv = tid >> 6;
  const int qA = blockIdx.x * 8 + wv * 2;   // even; qB = qA+1 (same bh)
  const int qB = qA + 1;
  const int bh = qA >> 10;
  const int bb = bh >> 3;
  const int hh = bh & 7;
  const float* rA = Sc + (size_t)qA * 1024;
  const float* rB = Sc + (size_t)qB * 1024;
  const float* Vbh = Vg + (size_t)bh * (TT * 64);

  float vA[16], vB[16];
#pragma unroll
  for (int j4 = 0; j4 < 4; ++j4) {
    float4 tA = *(const float4*)&rA[j4 * 256 + lane * 4];
    float4 tB = *(const float4*)&rB[j4 * 256 + lane * 4];
    vA[j4 * 4 + 0] = tA.x; vA[j4 * 4 + 1] = tA.y;
    vA[j4 * 4 + 2] = tA.z; vA[j4 * 4 + 3] = tA.w;
    vB[j4 * 4 + 0] = tB.x; vB[j4 * 4 + 1] = tB.y;
    vB[j4 * 4 + 2] = tB.z; vB[j4 * 4 + 3] = tB.w;
  }
  float gvA[4], gvB[4];
  int gjA[4], gjB[4];
#pragma unroll
  for (int g = 0; g < 4; ++g) {
    gvA[g] = vA[4 * g]; gjA[g] = 4 * g;
    gvB[g] = vB[4 * g]; gjB[g] = 4 * g;
#pragma unroll
    for (int e = 1; e < 4; ++e) {
      if (vA[4 * g + e] > gvA[g]) { gvA[g] = vA[4 * g + e]; gjA[g] = 4 * g + e; }
      if (vB[4 * g + e] > gvB[g]) { gvB[g] = vB[4 * g + e]; gjB[g] = 4 * g + e; }
    }
  }
  int mykA = 0, mykB = 0;
#pragma unroll 1
  for (int it = 0; it < NTOPK; ++it) {
    float bvA = gvA[0], bvB = gvB[0];
    int bjjA = gjA[0], bjjB = gjB[0];
#pragma unroll
    for (int g = 1; g < 4; ++g) {
      if (gvA[g] > bvA) { bvA = gvA[g]; bjjA = gjA[g]; }
      if (gvB[g] > bvB) { bvB = gvB[g]; bjjB = gjB[g]; }
    }
    int bjA = ((bjjA >> 2) << 8) + (lane << 2) + (bjjA & 3);
    int bjB = ((bjjB >> 2) << 8) + (lane << 2) + (bjjB & 3);
#pragma unroll
    for (int off = 32; off >= 1; off >>= 1) {
      float ovA = __shfl_xor(bvA, off, 64);
      int ojA = __shfl_xor(bjA, off, 64);
      float ovB = __shfl_xor(bvB, off, 64);
      int ojB = __shfl_xor(bjB, off, 64);
      if (ovA > bvA || (ovA == bvA && ojA < bjA)) { bvA = ovA; bjA = ojA; }
      if (ovB > bvB || (ovB == bvB && ojB < bjB)) { bvB = ovB; bjB = ojB; }
    }
    if (lane == it) { mykA = bjA; mykB = bjB; }
    // knockout A
    {
      int owner = (bjA >> 2) & 63;
      int slot = ((bjA >> 8) << 2) | (bjA & 3);
      if (lane == owner) {
#pragma unroll
        for (int jj = 0; jj < 16; ++jj)
          if (jj == slot) vA[jj] = -INFINITY;
        int g2 = slot >> 2;
#pragma unroll
        for (int g = 0; g < 4; ++g) {
          if (g == g2) {
            float ngv = vA[4 * g];
            int ngj = 4 * g;
#pragma unroll
            for (int e = 1; e < 4; ++e) {
              if (vA[4 * g + e] > ngv) { ngv = vA[4 * g + e]; ngj = 4 * g + e; }
            }
            gvA[g] = ngv;
            gjA[g] = ngj;
          }
        }
      }
    }
    // knockout B
    {
      int owner = (bjB >> 2) & 63;
      int slot = ((bjB >> 8) << 2) | (bjB & 3);
      if (lane == owner) {
#pragma unroll
        for (int jj = 0; jj < 16; ++jj)
          if (jj == slot) vB[jj] = -INFINITY;
        int g2 = slot >> 2;
#pragma unroll
        for (int g = 0; g < 4; ++g) {
          if (g == g2) {
            float ngv = vB[4 * g];
            int ngj = 4 * g;
#pragma unroll
            for (int e = 1; e < 4; ++e) {
              if (vB[4 * g + e] > ngv) { ngv = vB[4 * g + e]; ngj = 4 * g + e; }
            }
            gvB[g] = ngv;
            gjB[g] = ngj;
          }
        }
      }
    }
  }
  // fp32 smooth path for both queries (selection already fixed)
  const double cphi = ccd[0];
  const double ctau = ccd[1];
  const double bta0 = (double)btaP[0];
  const double btb0 = (double)btbP[0];
  double4 sqA = sqd4[qA];
  double4 sqB = sqd4[qB];
  float logitA = -INFINITY, logitB = -INFINITY;
  if (lane < 16) {
    double4 skA = skd4[bh * TT + mykA];
    double4 skB = skd4[bh * TT + mykB];
    float xsA = (float)(sqA.x + skA.x + cphi);
    float taA = (float)(sqA.y + skA.y + bta0);
    float tbA = (float)(sqA.z + skA.z + btb0);
    float tlA = (float)(sqA.w + skA.w + ctau);
    float xsB = (float)(sqB.x + skB.x + cphi);
    float taB = (float)(sqB.y + skB.y + bta0);
    float tbB = (float)(sqB.z + skB.z + btb0);
    float tlB = (float)(sqB.w + skB.w + ctau);
    float phiA = 1.f / (1.f + __expf(-xsA));
    float tiA = 1.f / (1.f + __expf(-(taA + tbA)));
    float tauA = fmaxf(tlA, 0.f) + log1pf(__expf(-fabsf(tlA))) + 1e-6f;
    logitA = phiA / tauA * (1.f - __expf(-tauA * tiA));
    float phiB = 1.f / (1.f + __expf(-xsB));
    float tiB = 1.f / (1.f + __expf(-(taB + tbB)));
    float tauB = fmaxf(tlB, 0.f) + log1pf(__expf(-fabsf(tlB))) + 1e-6f;
    logitB = phiB / tauB * (1.f - __expf(-tauB * tiB));
  }
  float mA = logitA, mB = logitB;
#pragma unroll
  for (int off = 8; off >= 1; off >>= 1) {
    mA = fmaxf(mA, __shfl_xor(mA, off, 64));
    mB = fmaxf(mB, __shfl_xor(mB, off, 64));
  }
  float eA = (lane < 16) ? __expf(logitA - mA) : 0.f;
  float eB = (lane < 16) ? __expf(logitB - mB) : 0.f;
  float sA = eA, sB = eB;
#pragma unroll
  for (int off = 8; off >= 1; off >>= 1) {
    sA += __shfl_xor(sA, off, 64);
    sB += __shfl_xor(sB, off, 64);
  }
  float wA = eA / sA;
  float wB = eB / sB;
  float outA = 0.f, outB = 0.f;
#pragma unroll
  for (int k2 = 0; k2 < NTOPK; ++k2) {
    float wkA = __shfl(wA, k2, 64);
    int ikA = __shfl(mykA, k2, 64);
    float wkB = __shfl(wB, k2, 64);
    int ikB = __shfl(mykB, k2, 64);
    outA = fmaf(wkA, Vbh[(size_t)ikA * 64 + lane], outA);
    outB = fmaf(wkB, Vbh[(size_t)ikB * 64 + lane], outB);
  }
  const int qaA = qA & 1023;
  C[(bb * TT + qaA) * 512 + hh * 64 + lane] = outA;
  C[(bb * TT + qaA + 1) * 512 + hh * 64 + lane] = outB;
}

// ---------------------------------------------------------------------------
// Fallback fused attention (round-5 path) for small workspaces.
// ---------------------------------------------------------------------------
__global__ __launch_bounds__(256) void k_attn(
    const float* __restrict__ Qg, const float* __restrict__ Kg,
    const float* __restrict__ Vg, const double4* __restrict__ sqd4,
    const double4* __restrict__ skd4, const double* __restrict__ ccd,
    const float* __restrict__ btaP, const float* __restrict__ btbP,
    float* __restrict__ C) {
  __shared__ float qs[8][64];
  __shared__ float sc[8][1024];
  const int bh = blockIdx.y;
  const int q0 = blockIdx.x * 8;
  const int tid = threadIdx.x;
  const int lane = tid & 63;
  const int wv = tid >> 6;
  if (tid < 128) {
    int q = tid >> 4, d4 = (tid & 15) << 2;
    *(float4*)&qs[q][d4] = *(const float4*)&Qg[(size_t)(bh * TT + q0 + q) * 64 + d4];
  }
  __syncthreads();
#pragma unroll 1
  for (int c = 0; c < 4; ++c) {
    const int kb = (c * 4 + wv) * 64;
    const float* krow = &Kg[(size_t)(bh * TT + kb + lane) * 64];
    float4 kr[16];
#pragma unroll
    for (int i = 0; i < 16; ++i) kr[i] = *(const float4*)&krow[i * 4];
#pragma unroll
    for (int q = 0; q < 8; ++q) {
      float s = 0.f;
#pragma unroll
      for (int i = 0; i < 16; ++i) {
        float4 q4 = *(const float4*)&qs[q][i * 4];
        s = fmaf(q4.x, kr[i].x, s);
        s = fmaf(q4.y, kr[i].y, s);
        s = fmaf(q4.z, kr[i].z, s);
        s = fmaf(q4.w, kr[i].w, s);
      }
      sc[q][kb + lane] = s;
    }
  }
  __syncthreads();
  const double cphi = ccd[0];
  const double ctau = ccd[1];
  const double bta0 = (double)btaP[0];
  const double btb0 = (double)btbP[0];
  const int bb = bh >> 3;
  const int hh = bh & 7;
  const float* Vbh = Vg + (size_t)bh * (TT * 64);
#pragma unroll 1
  for (int qq = 0; qq < 2; ++qq) {
    const int ql = wv * 2 + qq;
    const int qa = q0 + ql;
    const float* rowp = &sc[ql][0];
    float v[16];
#pragma unroll
    for (int jj = 0; jj < 16; ++jj) v[jj] = rowp[jj * 64 + lane];
    float gv[4];
    int gj[4];
#pragma unroll
    for (int g = 0; g < 4; ++g) {
      gv[g] = v[4 * g];
      gj[g] = 4 * g;
#pragma unroll
      for (int e = 1; e < 4; ++e) {
        if (v[4 * g + e] > gv[g]) { gv[g] = v[4 * g + e]; gj[g] = 4 * g + e; }
      }
    }
    int myk = 0;
#pragma unroll 1
    for (int it = 0; it < NTOPK; ++it) {
      float bvv = gv[0];
      int bjj = gj[0];
#pragma unroll
      for (int g = 1; g < 4; ++g) {
        if (gv[g] > bvv) { bvv = gv[g]; bjj = gj[g]; }
      }
      int bj = bjj * 64 + lane;
#pragma unroll
      for (int off = 32; off >= 1; off >>= 1) {
        float ov = __shfl_xor(bvv, off, 64);
        int oj = __shfl_xor(bj, off, 64);
        if (ov > bvv || (ov == bvv && oj < bj)) { bvv = ov; bj = oj; }
      }
      if (lane == it) myk = bj;
      int owner = bj & 63;
      int slot = bj >> 6;
      if (lane == owner) {
#pragma unroll
        for (int jj = 0; jj < 16; ++jj)
          if (jj == slot) v[jj] = -INFINITY;
        int g2 = slot >> 2;
#pragma unroll
        for (int g = 0; g < 4; ++g) {
          if (g == g2) {
            float ngv = v[4 * g];
            int ngj = 4 * g;
#pragma unroll
            for (int e = 1; e < 4; ++e) {
              if (v[4 * g + e] > ngv) { ngv = v[4 * g + e]; ngj = 4 * g + e; }
            }
            gv[g] = ngv;
            gj[g] = ngj;
          }
        }
      }
    }
    double4 sq = sqd4[bh * TT + qa];
    double logit = -INFINITY;
    if (lane < 16) {
      double4 sk = skd4[bh * TT + myk];
      double phi = 1.0 / (1.0 + exp(-(sq.x + sk.x + cphi)));
      double ta = sq.y + sk.y + bta0;
      double tb = sq.z + sk.z + btb0;
      double ti = 1.0 / (1.0 + exp(-(ta * 1.0 + tb)));
      double tl = sq.w + sk.w + ctau;
      double tau = fmax(tl, 0.0) + log1p(exp(-fabs(tl))) + 1e-6;
      logit = phi / tau * (1.0 - exp(-tau * ti));
    }
    double m = logit;
#pragma unroll
    for (int off = 8; off >= 1; off >>= 1) {
      double om = __shfl_xor(m, off, 64);
      m = fmax(m, om);
    }
    double e = (lane < 16) ? exp(logit - m) : 0.0;
    double ssum = e;
#pragma unroll
    for (int off = 8; off >= 1; off >>= 1) ssum += __shfl_xor(ssum, off, 64);
    double w = e / ssum;
    double outv = 0.0;
#pragma unroll
    for (int k2 = 0; k2 < NTOPK; ++k2) {
      double wk = __shfl(w, k2, 64);
      int ik = __shfl(myk, k2, 64);
      outv += wk * (double)Vbh[(size_t)ik * 64 + lane];
    }
    C[(bb * TT + qa) * 512 + hh * 64 + lane] = (float)outv;
  }
}

// ---------------------------------------------------------------------------
extern "C" void kernel_launch(void* const* d_in, const int* in_sizes, int n_in,
                              void* d_out, int out_size, void* d_ws, size_t ws_size,
                              hipStream_t stream) {
  (void)in_sizes; (void)n_in; (void)out_size;
  const float* x   = (const float*)d_in[0];
  const float* Wq  = (const float*)d_in[1];
  const float* bq  = (const float*)d_in[2];
  const float* Wk  = (const float*)d_in[3];
  const float* bk  = (const float*)d_in[4];
  const float* Wv  = (const float*)d_in[5];
  const float* bv  = (const float*)d_in[6];
  const float* Wo  = (const float*)d_in[7];
  const float* bo  = (const float*)d_in[8];
  const float* Wpi = (const float*)d_in[9];
  const float* bpi = (const float*)d_in[10];
  const float* Wpo = (const float*)d_in[11];
  const float* bpo = (const float*)d_in[12];
  const float* Wta = (const float*)d_in[13];
  const float* bta = (const float*)d_in[14];
  const float* Wtb = (const float*)d_in[15];
  const float* btb = (const float*)d_in[16];
  const float* Wti = (const float*)d_in[17];
  const float* bti = (const float*)d_in[18];
  const float* Wto = (const float*)d_in[19];
  const float* bto = (const float*)d_in[20];

  double* wsd = (double*)d_ws;
  double4* sqd4 = (double4*)wsd;             // 65536 doubles
  double4* skd4 = (double4*)(wsd + 65536);   // 65536 doubles
  double* wphid = wsd + 131072;              // 128
  double* wtaud = wsd + 131200;              // 128
  double* ccd   = wsd + 131328;              // 2 (pad to 131332)
  float* fs = (float*)(wsd + 131332);
  float* Qf = fs;                  // 1,048,576 floats
  float* Kf = fs + 1048576;
  float* Vf = fs + 2097152;
  float* Cf = fs + 3145728;
  float* Sc = fs + 4194304;        // 16,777,216 floats (scores, 64 MB)
  const size_t need = (size_t)131332 * 8 + (size_t)(4194304 + 16777216) * 4;

  hipLaunchKernelGGL(k_collapse64, dim3(17), dim3(256), 0, stream,
                     Wpi, bpi, Wpo, bpo, Wti, bti, Wto, bto, wphid, wtaud, ccd);
  hipLaunchKernelGGL(k_gemm_qkv, dim3(24, 32), dim3(256), 0, stream,
                     x, Wq, bq, Wk, bk, Wv, bv, Qf, Kf, Vf);
  hipLaunchKernelGGL(k_tokscal64, dim3(NTOK / 64), dim3(64), 0, stream,
                     Qf, Kf, wphid, Wta, Wtb, wtaud, sqd4, skd4);
  if (ws_size >= need) {
    hipLaunchKernelGGL(k_score, dim3(8, 8, 16), dim3(256), 0, stream, Qf, Kf, Sc);
    hipLaunchKernelGGL(k_topk, dim3(NTOK / 8), dim3(256), 0, stream,
                       Sc, Vf, sqd4, skd4, ccd, bta, btb, Cf);
  } else {
    hipLaunchKernelGGL(k_attn, dim3(TT / 8, NBH), dim3(256), 0, stream,
                       Qf, Kf, Vf, sqd4, skd4, ccd, bta, btb, Cf);
  }
  hipLaunchKernelGGL(k_gemm, dim3(8, 32), dim3(256), 0, stream,
                     Cf, Wo, bo, (float*)d_out, 0);
}